// Round 2
// baseline (283.989 us; speedup 1.0000x reference)
//
#include <hip/hip_runtime.h>
#include <hip/hip_bf16.h>

typedef __bf16 bf16;
typedef __attribute__((ext_vector_type(8))) __bf16 bf16x8;
typedef __attribute__((ext_vector_type(4))) __bf16 bf16x4;
typedef __attribute__((ext_vector_type(4))) float f32x4;

#define NEGV (-1e18f)

__device__ __forceinline__ bf16 f2b(float f) {
    unsigned u = __builtin_bit_cast(unsigned, f);
    u += 0x7fffu + ((u >> 16) & 1u);
    unsigned short h = (unsigned short)(u >> 16);
    return __builtin_bit_cast(bf16, h);
}

__device__ __forceinline__ f32x4 mfma16(bf16x8 a, bf16x8 b, f32x4 c) {
    return __builtin_amdgcn_mfma_f32_16x16x32_bf16(a, b, c, 0, 0, 0);
}

// ---------------------------------------------------------------------------
// Weight transpose + f32->bf16 convert: out[w][n][k] = in[w][k][n]
// ---------------------------------------------------------------------------
__global__ __launch_bounds__(256) void wconv(const float* __restrict__ W0,
                                             const float* __restrict__ W1,
                                             const float* __restrict__ W2,
                                             const float* __restrict__ W3,
                                             bf16* __restrict__ out) {
    __shared__ float tile[64][65];
    const float* Ws[4] = {W0, W1, W2, W3};
    const float* W = Ws[blockIdx.z];
    bf16* O = out + ((size_t)blockIdx.z << 20);
    int t = threadIdx.x;
    int k0 = blockIdx.x * 64, n0 = blockIdx.y * 64;
#pragma unroll
    for (int p = 0; p < 4; p++) {
        int r = (t >> 4) + p * 16, c = (t & 15) * 4;
        float4 v = *(const float4*)&W[(size_t)(k0 + r) * 1024 + n0 + c];
        tile[r][c] = v.x; tile[r][c + 1] = v.y; tile[r][c + 2] = v.z; tile[r][c + 3] = v.w;
    }
    __syncthreads();
#pragma unroll
    for (int p = 0; p < 4; p++) {
        int r = (t >> 4) + p * 16, c = (t & 15) * 4;
        bf16x4 o;
        o[0] = f2b(tile[c][r]); o[1] = f2b(tile[c + 1][r]);
        o[2] = f2b(tile[c + 2][r]); o[3] = f2b(tile[c + 3][r]);
        *(bf16x4*)&O[(size_t)(n0 + r) * 1024 + k0 + c] = o;
    }
}

// ---------------------------------------------------------------------------
// Unified MFMA GEMM, 128x128 tile, BK=32, 256 threads (4 waves, 2x2 of 64x64).
// C[m,n] = sum_k A[m,k] * Bt[n,k]
// MODE 0: A=f32, C=bf16 scaled               (Q/K projections)
// MODE 1: A=bf16, C=f32                      (ctx @ Wo)
// MODE 2: batched: masked logits/16 -> f32   (attention_weights)
// MODE 3: A=f32, C^T=bf16 into [1024][4096]  (V projection, transposed out)
// ---------------------------------------------------------------------------
template <int MODE>
__global__ __launch_bounds__(256) void gemm_k(const void* __restrict__ Ap,
                                              const bf16* __restrict__ Btp,
                                              void* __restrict__ Cp,
                                              const int* __restrict__ maskp,
                                              float scale) {
    __shared__ bf16 As[128][56];
    __shared__ bf16 Bs[128][56];
    int t = threadIdx.x;
    int m0 = blockIdx.x * 128, n0 = blockIdx.y * 128;
    const float* Af = (const float*)Ap;
    const bf16* Ab = (const bf16*)Ap;
    const bf16* Bt = Btp;
    float* Cf = (float*)Cp;
    bf16* Cb = (bf16*)Cp;
    const int* mask = maskp;
    if (MODE == 2) {
        size_t z = blockIdx.z;
        Ab += z << 20; Bt += z << 20; Cf += z << 20; mask += z * 1024;
    }
    int wid = t >> 6, lane = t & 63;
    int wr = wid >> 1, wc = wid & 1, lr = lane & 15, lg = lane >> 4;
    f32x4 zero = {0.f, 0.f, 0.f, 0.f};
    f32x4 acc[4][4];
#pragma unroll
    for (int m = 0; m < 4; m++)
#pragma unroll
        for (int n = 0; n < 4; n++) acc[m][n] = zero;

    for (int k0 = 0; k0 < 1024; k0 += 32) {
        __syncthreads();
        if (MODE == 0 || MODE == 3) {
#pragma unroll
            for (int p = 0; p < 4; p++) {
                int r = (t >> 3) + p * 32, kk = (t & 7) * 4;
                float4 v = *(const float4*)&Af[(size_t)(m0 + r) * 1024 + k0 + kk];
                bf16x4 o;
                o[0] = f2b(v.x); o[1] = f2b(v.y); o[2] = f2b(v.z); o[3] = f2b(v.w);
                *(bf16x4*)&As[r][kk] = o;
            }
        } else {
#pragma unroll
            for (int p = 0; p < 2; p++) {
                int r = (t >> 2) + p * 64, kk = (t & 3) * 8;
                *(bf16x8*)&As[r][kk] = *(const bf16x8*)&Ab[(size_t)(m0 + r) * 1024 + k0 + kk];
            }
        }
#pragma unroll
        for (int p = 0; p < 2; p++) {
            int r = (t >> 2) + p * 64, kk = (t & 3) * 8;
            *(bf16x8*)&Bs[r][kk] = *(const bf16x8*)&Bt[(size_t)(n0 + r) * 1024 + k0 + kk];
        }
        __syncthreads();
        bf16x8 af[4], bfr[4];
#pragma unroll
        for (int m = 0; m < 4; m++) af[m] = *(const bf16x8*)&As[wr * 64 + m * 16 + lr][lg * 8];
#pragma unroll
        for (int n = 0; n < 4; n++) bfr[n] = *(const bf16x8*)&Bs[wc * 64 + n * 16 + lr][lg * 8];
#pragma unroll
        for (int m = 0; m < 4; m++)
#pragma unroll
            for (int n = 0; n < 4; n++) acc[m][n] = mfma16(af[m], bfr[n], acc[m][n]);
    }
#pragma unroll
    for (int n = 0; n < 4; n++) {
        int colg = n0 + wc * 64 + n * 16 + lr;
        int mk = (MODE == 2) ? mask[colg] : 0;
#pragma unroll
        for (int m = 0; m < 4; m++) {
            int rowg = m0 + wr * 64 + m * 16 + lg * 4;
            if (MODE == 3) {
                bf16x4 o;
#pragma unroll
                for (int j = 0; j < 4; j++) o[j] = f2b(acc[m][n][j]);
                *(bf16x4*)&Cb[(size_t)colg * 4096 + rowg] = o;
            } else {
#pragma unroll
                for (int j = 0; j < 4; j++) {
                    float v = acc[m][n][j];
                    size_t idx = (size_t)(rowg + j) * 1024 + colg;
                    if (MODE == 0) Cb[idx] = f2b(v * scale);
                    else if (MODE == 1) Cf[idx] = v;
                    else Cf[idx] = mk ? NEGV : v * (1.f / 16.f);
                }
            }
        }
    }
}

// ---------------------------------------------------------------------------
// Flash attention per (b, h, 64-row q-tile). 4 waves x 16 q-rows each.
// K and V^T fragments loaded DIRECTLY from global (L2-resident); only the
// P relayout goes through per-wave LDS, XOR-swizzled (byte ^= (row&7)<<4).
// No __syncthreads in the loop — waves fully independent.
// ---------------------------------------------------------------------------
__global__ __launch_bounds__(256) void flash_k(const bf16* __restrict__ Q,
                                               const bf16* __restrict__ K,
                                               const bf16* __restrict__ VT,
                                               bf16* __restrict__ CTX,
                                               const int* __restrict__ maskp) {
    __shared__ bf16 Ps[4][16 * 128];   // per-wave, rows of 256B, XOR-swizzled
    int bid = blockIdx.x;
    int qt = bid & 15, h = (bid >> 4) & 15, b = bid >> 8;
    int t = threadIdx.x, wid = t >> 6, lane = t & 63;
    int lr = lane & 15, lg = lane >> 4;
    int qbase = qt * 64 + wid * 16;
    const size_t bS = (size_t)b * 1024;
    char* PsW = (char*)&Ps[wid][0];

    bf16x8 qf[2];
#pragma unroll
    for (int c = 0; c < 2; c++)
        qf[c] = *(const bf16x8*)&Q[(bS + qbase + lr) * 1024 + h * 64 + c * 32 + lg * 8];

    f32x4 zero = {0.f, 0.f, 0.f, 0.f};
    f32x4 acc[4];
#pragma unroll
    for (int d = 0; d < 4; d++) acc[d] = zero;
    float mrow[4] = {-INFINITY, -INFINITY, -INFINITY, -INFINITY};
    float lrow[4] = {0.f, 0.f, 0.f, 0.f};

    for (int kt = 0; kt < 8; kt++) {
        const bf16* Kb = K + (bS + kt * 128) * 1024 + h * 64;
        // QK^T: S[q=lg*4+j][k=n*16+lr], K-frags straight from global
        f32x4 s[8];
#pragma unroll
        for (int n = 0; n < 8; n++) {
            bf16x8 kf0 = *(const bf16x8*)&Kb[(size_t)(n * 16 + lr) * 1024 + lg * 8];
            bf16x8 kf1 = *(const bf16x8*)&Kb[(size_t)(n * 16 + lr) * 1024 + 32 + lg * 8];
            f32x4 z = zero;
            z = mfma16(qf[0], kf0, z);
            z = mfma16(qf[1], kf1, z);
            s[n] = z;
        }
        // V^T frags from global, issued early so softmax hides the latency
        bf16x8 vf[4][4];
#pragma unroll
        for (int c = 0; c < 4; c++)
#pragma unroll
            for (int d = 0; d < 4; d++)
                vf[c][d] = *(const bf16x8*)&VT[(size_t)(h * 64 + d * 16 + lr) * 4096 +
                                               bS + kt * 128 + c * 32 + lg * 8];
#pragma unroll
        for (int n = 0; n < 8; n++) {
            int mk = maskp[b * 1024 + kt * 128 + n * 16 + lr];
            if (mk) { s[n][0] = NEGV; s[n][1] = NEGV; s[n][2] = NEGV; s[n][3] = NEGV; }
        }
        // online softmax per q-row (reduce over k: regs n + lanes lr via xor)
#pragma unroll
        for (int j = 0; j < 4; j++) {
            float mj = s[0][j];
#pragma unroll
            for (int n = 1; n < 8; n++) mj = fmaxf(mj, s[n][j]);
            mj = fmaxf(mj, __shfl_xor(mj, 1));
            mj = fmaxf(mj, __shfl_xor(mj, 2));
            mj = fmaxf(mj, __shfl_xor(mj, 4));
            mj = fmaxf(mj, __shfl_xor(mj, 8));
            float mn = fmaxf(mrow[j], mj);
            float sc = __expf(mrow[j] - mn);
            mrow[j] = mn;
            float rs = 0.f;
#pragma unroll
            for (int n = 0; n < 8; n++) {
                float pv = __expf(s[n][j] - mn);
                s[n][j] = pv;
                rs += pv;
            }
            rs += __shfl_xor(rs, 1);
            rs += __shfl_xor(rs, 2);
            rs += __shfl_xor(rs, 4);
            rs += __shfl_xor(rs, 8);
            lrow[j] = lrow[j] * sc + rs;
#pragma unroll
            for (int d = 0; d < 4; d++) acc[d][j] *= sc;
        }
        // P -> per-wave LDS (bf16), XOR-swizzled rows
#pragma unroll
        for (int n = 0; n < 8; n++)
#pragma unroll
            for (int j = 0; j < 4; j++) {
                int row = lg * 4 + j, col = n * 16 + lr;
                int byteoff = (row * 256 + 2 * col) ^ ((row & 7) << 4);
                *(bf16*)(PsW + byteoff) = (bf16)s[n][j];
            }
        // PV: A-frag from swizzled Ps, B-frag = preloaded V^T regs
#pragma unroll
        for (int c = 0; c < 4; c++) {
            int rbyte = (lr * 256 + c * 64 + lg * 16) ^ ((lr & 7) << 4);
            bf16x8 pa = *(const bf16x8*)(PsW + rbyte);
#pragma unroll
            for (int d = 0; d < 4; d++) acc[d] = mfma16(pa, vf[c][d], acc[d]);
        }
    }
#pragma unroll
    for (int j = 0; j < 4; j++) {
        float inv = 1.f / lrow[j];
#pragma unroll
        for (int d = 0; d < 4; d++)
            CTX[(bS + qbase + lg * 4 + j) * 1024 + h * 64 + d * 16 + lr] = f2b(acc[d][j] * inv);
    }
}

extern "C" void kernel_launch(void* const* d_in, const int* in_sizes, int n_in,
                              void* d_out, int out_size, void* d_ws, size_t ws_size,
                              hipStream_t stream) {
    const float* queries = (const float*)d_in[0];
    const float* keys    = (const float*)d_in[1];
    const float* values  = (const float*)d_in[2];
    const float* Wq = (const float*)d_in[3];
    const float* Wk = (const float*)d_in[4];
    const float* Wv = (const float*)d_in[5];
    const float* Wo = (const float*)d_in[6];
    const int* mask = (const int*)d_in[7];

    float* out = (float*)d_out;                       // [4,1024,1024]
    float* aw  = out + ((size_t)4 << 20);             // [4,1024,1024]

    bf16* wsb = (bf16*)d_ws;
    bf16* WtQ = wsb;                                  // 4 x 1M bf16 (transposed weights)
    bf16* Qw  = wsb + ((size_t)4 << 20);              // [4096,1024] bf16 (scaled)
    bf16* Kw  = wsb + ((size_t)8 << 20);
    bf16* VtG = wsb + ((size_t)12 << 20);             // [1024][4096] bf16 (V transposed)
    bf16* CTX = wsb + ((size_t)16 << 20);

    wconv<<<dim3(16, 16, 4), 256, 0, stream>>>(Wq, Wk, Wv, Wo, WtQ);
    gemm_k<0><<<dim3(32, 8, 1), 256, 0, stream>>>(queries, WtQ, Qw, nullptr, 0.125f);
    gemm_k<0><<<dim3(32, 8, 1), 256, 0, stream>>>(keys, WtQ + (1u << 20), Kw, nullptr, 1.0f);
    gemm_k<3><<<dim3(32, 8, 1), 256, 0, stream>>>(values, WtQ + (2u << 20), VtG, nullptr, 1.0f);
    gemm_k<2><<<dim3(8, 8, 4), 256, 0, stream>>>(Qw, Kw, aw, mask, 1.0f);
    flash_k<<<dim3(1024), 256, 0, stream>>>(Qw, Kw, VtG, CTX, mask);
    gemm_k<1><<<dim3(32, 8, 1), 256, 0, stream>>>(CTX, WtQ + (3u << 20), out, nullptr, 1.0f);
}

// Round 3
// 173.598 us; speedup vs baseline: 1.6359x; 1.6359x over previous
//
#include <hip/hip_runtime.h>
#include <hip/hip_bf16.h>

typedef __bf16 bf16;
typedef __attribute__((ext_vector_type(8))) __bf16 bf16x8;
typedef __attribute__((ext_vector_type(4))) __bf16 bf16x4;
typedef __attribute__((ext_vector_type(4))) float f32x4;

#define NEGV (-1e18f)

__device__ __forceinline__ bf16 f2b(float f) {
    unsigned u = __builtin_bit_cast(unsigned, f);
    u += 0x7fffu + ((u >> 16) & 1u);
    unsigned short h = (unsigned short)(u >> 16);
    return __builtin_bit_cast(bf16, h);
}

__device__ __forceinline__ f32x4 mfma16(bf16x8 a, bf16x8 b, f32x4 c) {
    return __builtin_amdgcn_mfma_f32_16x16x32_bf16(a, b, c, 0, 0, 0);
}

__device__ __forceinline__ void gl16(const void* g, void* l) {
    __builtin_amdgcn_global_load_lds((const __attribute__((address_space(1))) void*)g,
                                     (__attribute__((address_space(3))) void*)l, 16, 0, 0);
}

// ---------------------------------------------------------------------------
// Weight transpose + f32->bf16 convert: out[w][n][k] = in[w][k][n]
// ---------------------------------------------------------------------------
__global__ __launch_bounds__(256) void wconv(const float* __restrict__ W0,
                                             const float* __restrict__ W1,
                                             const float* __restrict__ W2,
                                             const float* __restrict__ W3,
                                             bf16* __restrict__ out) {
    __shared__ float tile[64][65];
    const float* Ws[4] = {W0, W1, W2, W3};
    const float* W = Ws[blockIdx.z];
    bf16* O = out + ((size_t)blockIdx.z << 20);
    int t = threadIdx.x;
    int k0 = blockIdx.x * 64, n0 = blockIdx.y * 64;
#pragma unroll
    for (int p = 0; p < 4; p++) {
        int r = (t >> 4) + p * 16, c = (t & 15) * 4;
        float4 v = *(const float4*)&W[(size_t)(k0 + r) * 1024 + n0 + c];
        tile[r][c] = v.x; tile[r][c + 1] = v.y; tile[r][c + 2] = v.z; tile[r][c + 3] = v.w;
    }
    __syncthreads();
#pragma unroll
    for (int p = 0; p < 4; p++) {
        int r = (t >> 4) + p * 16, c = (t & 15) * 4;
        bf16x4 o;
        o[0] = f2b(tile[c][r]); o[1] = f2b(tile[c + 1][r]);
        o[2] = f2b(tile[c + 2][r]); o[3] = f2b(tile[c + 3][r]);
        *(bf16x4*)&O[(size_t)(n0 + r) * 1024 + k0 + c] = o;
    }
}

// ---------------------------------------------------------------------------
// f32 -> bf16 flat convert for Q/K/V activations. grid (2048, 3).
// ---------------------------------------------------------------------------
__global__ __launch_bounds__(256) void cvt3(const float* __restrict__ Qf,
                                            const float* __restrict__ Kf,
                                            const float* __restrict__ Vf,
                                            bf16* __restrict__ Qa,
                                            bf16* __restrict__ Ka,
                                            bf16* __restrict__ Va) {
    int z = blockIdx.y;
    const float* in = (z == 0) ? Qf : (z == 1) ? Kf : Vf;
    bf16* out = (z == 0) ? Qa : (z == 1) ? Ka : Va;
    size_t i = ((size_t)blockIdx.x * 256 + threadIdx.x) * 8;
    float4 a = *(const float4*)&in[i];
    float4 b = *(const float4*)&in[i + 4];
    bf16x8 o;
    o[0] = f2b(a.x); o[1] = f2b(a.y); o[2] = f2b(a.z); o[3] = f2b(a.w);
    o[4] = f2b(b.x); o[5] = f2b(b.y); o[6] = f2b(b.z); o[7] = f2b(b.w);
    *(bf16x8*)&out[i] = o;
}

// ---------------------------------------------------------------------------
// MFMA GEMM, 128x128 tile, BK=32, 4 waves (2x2 of 64x64), global_load_lds
// width-16 staging (m97 structure). A and Bt both bf16 row-major [.][1024].
// MODE 0: z=0,1,2 -> Qw (x0.125), Kw, VtG (transposed out [1024][4096])
// MODE 1: C=f32 (ctx @ Wo)
// MODE 2: batched z=b: masked logits/16 -> f32 attention_weights
// ---------------------------------------------------------------------------
template <int MODE>
__global__ __launch_bounds__(256) void gemm_k(const bf16* __restrict__ A0,
                                              const bf16* __restrict__ A1,
                                              const bf16* __restrict__ A2,
                                              const bf16* __restrict__ Bt0,
                                              void* __restrict__ C0,
                                              void* __restrict__ C1,
                                              void* __restrict__ C2,
                                              const int* __restrict__ maskp) {
    __shared__ bf16 As[128 * 32];
    __shared__ bf16 Bs[128 * 32];
    int t = threadIdx.x;
    int m0 = blockIdx.x * 128, n0 = blockIdx.y * 128;
    int z = blockIdx.z;
    const bf16* A;
    const bf16* Bt;
    const int* mask = maskp;
    if (MODE == 0) { A = (z == 0) ? A0 : (z == 1) ? A1 : A2; Bt = Bt0 + ((size_t)z << 20); }
    else if (MODE == 1) { A = A0; Bt = Bt0; }
    else { A = A0 + ((size_t)z << 20); Bt = Bt0 + ((size_t)z << 20); mask = maskp + z * 1024; }
    int wid = t >> 6, lane = t & 63;
    int wr = wid >> 1, wc = wid & 1, lr = lane & 15, lg = lane >> 4;
    f32x4 zero = {0.f, 0.f, 0.f, 0.f};
    f32x4 acc[4][4];
#pragma unroll
    for (int m = 0; m < 4; m++)
#pragma unroll
        for (int n = 0; n < 4; n++) acc[m][n] = zero;

    for (int k0 = 0; k0 < 1024; k0 += 32) {
        __syncthreads();
#pragma unroll
        for (int i = 0; i < 2; i++) {
            int c = wid * 128 + i * 64 + lane;
            int row = c >> 2, q = c & 3;
            gl16(&A[(size_t)(m0 + row) * 1024 + k0 + q * 8], (void*)&As[c * 8]);
            gl16(&Bt[(size_t)(n0 + row) * 1024 + k0 + q * 8], (void*)&Bs[c * 8]);
        }
        __syncthreads();
        bf16x8 af[4], bfr[4];
#pragma unroll
        for (int m = 0; m < 4; m++) af[m] = *(const bf16x8*)&As[(wr * 64 + m * 16 + lr) * 32 + lg * 8];
#pragma unroll
        for (int n = 0; n < 4; n++) bfr[n] = *(const bf16x8*)&Bs[(wc * 64 + n * 16 + lr) * 32 + lg * 8];
#pragma unroll
        for (int m = 0; m < 4; m++)
#pragma unroll
            for (int n = 0; n < 4; n++) acc[m][n] = mfma16(af[m], bfr[n], acc[m][n]);
    }
#pragma unroll
    for (int n = 0; n < 4; n++) {
        int colg = n0 + wc * 64 + n * 16 + lr;
        int mk = (MODE == 2) ? mask[colg] : 0;
#pragma unroll
        for (int m = 0; m < 4; m++) {
            int rowg = m0 + wr * 64 + m * 16 + lg * 4;
            if (MODE == 0 && z == 2) {
                bf16x4 o;
#pragma unroll
                for (int j = 0; j < 4; j++) o[j] = f2b(acc[m][n][j]);
                *(bf16x4*)&((bf16*)C2)[(size_t)colg * 4096 + rowg] = o;
            } else {
#pragma unroll
                for (int j = 0; j < 4; j++) {
                    float v = acc[m][n][j];
                    size_t idx = (size_t)(rowg + j) * 1024 + colg;
                    if (MODE == 0) {
                        bf16* C = (bf16*)((z == 0) ? C0 : C1);
                        C[idx] = f2b(v * ((z == 0) ? 0.125f : 1.0f));
                    } else if (MODE == 1) {
                        ((float*)C0)[idx] = v;
                    } else {
                        float* C = (float*)C0 + ((size_t)z << 20);
                        C[idx] = mk ? NEGV : v * (1.f / 16.f);
                    }
                }
            }
        }
    }
}

// ---------------------------------------------------------------------------
// Flash attention per (b, h, 64-row q-tile). 4 waves x 16 q-rows each.
// K [128][64] and V^T [64][128] staged in LDS (XOR-swizzled byte^=(row&7)<<4,
// both write and read sides); next tile reg-prefetched after 2nd barrier so
// loads overlap compute. Mask pre-expanded to a float bias LDS table.
// ---------------------------------------------------------------------------
__global__ __launch_bounds__(256) void flash_k(const bf16* __restrict__ Q,
                                               const bf16* __restrict__ K,
                                               const bf16* __restrict__ VT,
                                               bf16* __restrict__ CTX,
                                               const int* __restrict__ maskp) {
    __shared__ bf16 Ks[128 * 64];
    __shared__ bf16 Vs[64 * 128];
    __shared__ bf16 Ps[4][16 * 128];
    __shared__ float biasS[1024];
    int bid = blockIdx.x;
    int qt = bid & 15, h = (bid >> 4) & 15, b = bid >> 8;
    int t = threadIdx.x, wid = t >> 6, lane = t & 63;
    int lr = lane & 15, lg = lane >> 4;
    int qbase = qt * 64 + wid * 16;
    const size_t bS = (size_t)b * 1024;
    char* KsB = (char*)Ks;
    char* VsB = (char*)Vs;
    char* PsW = (char*)&Ps[wid][0];

    {   // mask -> bias table (once per block)
        int4 mv = *(const int4*)&maskp[b * 1024 + t * 4];
        float4 bv;
        bv.x = mv.x ? NEGV : 0.f; bv.y = mv.y ? NEGV : 0.f;
        bv.z = mv.z ? NEGV : 0.f; bv.w = mv.w ? NEGV : 0.f;
        *(float4*)&biasS[t * 4] = bv;
    }

    bf16x8 qf[2];
#pragma unroll
    for (int c = 0; c < 2; c++)
        qf[c] = *(const bf16x8*)&Q[(bS + qbase + lr) * 1024 + h * 64 + c * 32 + lg * 8];

    f32x4 zero = {0.f, 0.f, 0.f, 0.f};
    f32x4 acc[4];
#pragma unroll
    for (int d = 0; d < 4; d++) acc[d] = zero;
    float mrow[4] = {-INFINITY, -INFINITY, -INFINITY, -INFINITY};
    float lrow[4] = {0.f, 0.f, 0.f, 0.f};

    bf16x8 kg[4], vg[4];
#pragma unroll
    for (int i = 0; i < 4; i++) {
        int c = t + i * 256;
        kg[i] = *(const bf16x8*)&K[(bS + (c >> 3)) * 1024 + h * 64 + (c & 7) * 8];
        vg[i] = *(const bf16x8*)&VT[(size_t)(h * 64 + (c >> 4)) * 4096 + bS + (c & 15) * 8];
    }

    for (int kt = 0; kt < 8; kt++) {
        __syncthreads();
#pragma unroll
        for (int i = 0; i < 4; i++) {
            int c = t + i * 256;
            int kr = c >> 3, kq = c & 7;
            *(bf16x8*)(KsB + ((kr * 128 + kq * 16) ^ ((kr & 7) << 4))) = kg[i];
            int vr = c >> 4, vq = c & 15;
            *(bf16x8*)(VsB + ((vr * 256 + vq * 16) ^ ((vr & 7) << 4))) = vg[i];
        }
        __syncthreads();
        if (kt < 7) {
#pragma unroll
            for (int i = 0; i < 4; i++) {
                int c = t + i * 256;
                kg[i] = *(const bf16x8*)&K[(bS + (kt + 1) * 128 + (c >> 3)) * 1024 + h * 64 + (c & 7) * 8];
                vg[i] = *(const bf16x8*)&VT[(size_t)(h * 64 + (c >> 4)) * 4096 + bS + (kt + 1) * 128 + (c & 15) * 8];
            }
        }
        // QK^T from swizzled LDS
        f32x4 s[8];
#pragma unroll
        for (int n = 0; n < 8; n++) {
            int row = n * 16 + lr;
            bf16x8 kf0 = *(const bf16x8*)(KsB + ((row * 128 + lg * 16) ^ ((row & 7) << 4)));
            bf16x8 kf1 = *(const bf16x8*)(KsB + ((row * 128 + 64 + lg * 16) ^ ((row & 7) << 4)));
            f32x4 zz = zero;
            zz = mfma16(qf[0], kf0, zz);
            zz = mfma16(qf[1], kf1, zz);
            s[n] = zz;
        }
        // mask bias
#pragma unroll
        for (int n = 0; n < 8; n++) {
            float bz = biasS[kt * 128 + n * 16 + lr];
            s[n][0] += bz; s[n][1] += bz; s[n][2] += bz; s[n][3] += bz;
        }
        // online softmax per q-row
#pragma unroll
        for (int j = 0; j < 4; j++) {
            float mj = s[0][j];
#pragma unroll
            for (int n = 1; n < 8; n++) mj = fmaxf(mj, s[n][j]);
            mj = fmaxf(mj, __shfl_xor(mj, 1));
            mj = fmaxf(mj, __shfl_xor(mj, 2));
            mj = fmaxf(mj, __shfl_xor(mj, 4));
            mj = fmaxf(mj, __shfl_xor(mj, 8));
            float mn = fmaxf(mrow[j], mj);
            float sc = __expf(mrow[j] - mn);
            mrow[j] = mn;
            float rs = 0.f;
#pragma unroll
            for (int n = 0; n < 8; n++) {
                float pv = __expf(s[n][j] - mn);
                s[n][j] = pv;
                rs += pv;
            }
            rs += __shfl_xor(rs, 1);
            rs += __shfl_xor(rs, 2);
            rs += __shfl_xor(rs, 4);
            rs += __shfl_xor(rs, 8);
            lrow[j] = lrow[j] * sc + rs;
#pragma unroll
            for (int d = 0; d < 4; d++) acc[d][j] *= sc;
        }
        // P -> per-wave LDS (swizzled), then PV from swizzled Vs
#pragma unroll
        for (int n = 0; n < 8; n++)
#pragma unroll
            for (int j = 0; j < 4; j++) {
                int row = lg * 4 + j, col = n * 16 + lr;
                *(bf16*)(PsW + ((row * 256 + 2 * col) ^ ((row & 7) << 4))) = (bf16)s[n][j];
            }
#pragma unroll
        for (int c4 = 0; c4 < 4; c4++) {
            bf16x8 pa = *(const bf16x8*)(PsW + ((lr * 256 + c4 * 64 + lg * 16) ^ ((lr & 7) << 4)));
#pragma unroll
            for (int d = 0; d < 4; d++) {
                int row = d * 16 + lr;
                bf16x8 vb = *(const bf16x8*)(VsB + ((row * 256 + c4 * 64 + lg * 16) ^ ((row & 7) << 4)));
                acc[d] = mfma16(pa, vb, acc[d]);
            }
        }
    }
#pragma unroll
    for (int j = 0; j < 4; j++) {
        float inv = 1.f / lrow[j];
#pragma unroll
        for (int d = 0; d < 4; d++)
            CTX[(bS + qbase + lg * 4 + j) * 1024 + h * 64 + d * 16 + lr] = f2b(acc[d][j] * inv);
    }
}

extern "C" void kernel_launch(void* const* d_in, const int* in_sizes, int n_in,
                              void* d_out, int out_size, void* d_ws, size_t ws_size,
                              hipStream_t stream) {
    const float* queries = (const float*)d_in[0];
    const float* keys    = (const float*)d_in[1];
    const float* values  = (const float*)d_in[2];
    const float* Wq = (const float*)d_in[3];
    const float* Wk = (const float*)d_in[4];
    const float* Wv = (const float*)d_in[5];
    const float* Wo = (const float*)d_in[6];
    const int* mask = (const int*)d_in[7];

    float* out = (float*)d_out;                       // [4,1024,1024]
    float* aw  = out + ((size_t)4 << 20);             // [4,1024,1024]

    bf16* wsb = (bf16*)d_ws;
    bf16* WtQ = wsb;                                  // [0,4M) transposed weights
    bf16* Qa  = wsb + ((size_t)4 << 20);              // activations; reused as CTX
    bf16* Qw  = wsb + ((size_t)8 << 20);
    bf16* Kw  = wsb + ((size_t)12 << 20);
    bf16* VtG = wsb + ((size_t)16 << 20);             // [1024][4096] V transposed
    bf16* Ka  = (bf16*)aw;                            // scratch in aw (written later)
    bf16* Va  = (bf16*)aw + ((size_t)4 << 20);
    bf16* CTX = Qa;

    wconv<<<dim3(16, 16, 4), 256, 0, stream>>>(Wq, Wk, Wv, Wo, WtQ);
    cvt3<<<dim3(2048, 3), 256, 0, stream>>>(queries, keys, values, Qa, Ka, Va);
    gemm_k<0><<<dim3(32, 8, 3), 256, 0, stream>>>(Qa, Ka, Va, WtQ, Qw, Kw, VtG, nullptr);
    gemm_k<2><<<dim3(8, 8, 4), 256, 0, stream>>>(Qw, nullptr, nullptr, Kw, aw, nullptr, nullptr, mask);
    flash_k<<<dim3(1024), 256, 0, stream>>>(Qw, Kw, VtG, CTX, mask);
    gemm_k<1><<<dim3(32, 8, 1), 256, 0, stream>>>(CTX, nullptr, nullptr, WtQ + ((size_t)3 << 20), out, nullptr, nullptr, nullptr);
}

// Round 4
// 158.566 us; speedup vs baseline: 1.7910x; 1.0948x over previous
//
#include <hip/hip_runtime.h>
#include <hip/hip_bf16.h>

typedef __bf16 bf16;
typedef __attribute__((ext_vector_type(8))) __bf16 bf16x8;
typedef __attribute__((ext_vector_type(4))) __bf16 bf16x4;
typedef __attribute__((ext_vector_type(4))) float f32x4;

#define NEGV (-1e18f)
#define LOG2E 1.4426950408889634f

__device__ __forceinline__ bf16 f2b(float f) {
    unsigned u = __builtin_bit_cast(unsigned, f);
    u += 0x7fffu + ((u >> 16) & 1u);
    unsigned short h = (unsigned short)(u >> 16);
    return __builtin_bit_cast(bf16, h);
}

__device__ __forceinline__ f32x4 mfma16(bf16x8 a, bf16x8 b, f32x4 c) {
    return __builtin_amdgcn_mfma_f32_16x16x32_bf16(a, b, c, 0, 0, 0);
}

__device__ __forceinline__ void gl16(const void* g, void* l) {
    __builtin_amdgcn_global_load_lds((const __attribute__((address_space(1))) void*)g,
                                     (__attribute__((address_space(3))) void*)l, 16, 0, 0);
}

// ---------------------------------------------------------------------------
// Weight transpose + f32->bf16 convert: out[w][n][k] = in[w][k][n]
// ---------------------------------------------------------------------------
__global__ __launch_bounds__(256) void wconv(const float* __restrict__ W0,
                                             const float* __restrict__ W1,
                                             const float* __restrict__ W2,
                                             const float* __restrict__ W3,
                                             bf16* __restrict__ out) {
    __shared__ float tile[64][65];
    const float* Ws[4] = {W0, W1, W2, W3};
    const float* W = Ws[blockIdx.z];
    bf16* O = out + ((size_t)blockIdx.z << 20);
    int t = threadIdx.x;
    int k0 = blockIdx.x * 64, n0 = blockIdx.y * 64;
#pragma unroll
    for (int p = 0; p < 4; p++) {
        int r = (t >> 4) + p * 16, c = (t & 15) * 4;
        float4 v = *(const float4*)&W[(size_t)(k0 + r) * 1024 + n0 + c];
        tile[r][c] = v.x; tile[r][c + 1] = v.y; tile[r][c + 2] = v.z; tile[r][c + 3] = v.w;
    }
    __syncthreads();
#pragma unroll
    for (int p = 0; p < 4; p++) {
        int r = (t >> 4) + p * 16, c = (t & 15) * 4;
        bf16x4 o;
        o[0] = f2b(tile[c][r]); o[1] = f2b(tile[c + 1][r]);
        o[2] = f2b(tile[c + 2][r]); o[3] = f2b(tile[c + 3][r]);
        *(bf16x4*)&O[(size_t)(n0 + r) * 1024 + k0 + c] = o;
    }
}

// ---------------------------------------------------------------------------
// f32 -> bf16 flat convert for Q/K/V activations. grid (2048, 3).
// ---------------------------------------------------------------------------
__global__ __launch_bounds__(256) void cvt3(const float* __restrict__ Qf,
                                            const float* __restrict__ Kf,
                                            const float* __restrict__ Vf,
                                            bf16* __restrict__ Qa,
                                            bf16* __restrict__ Ka,
                                            bf16* __restrict__ Va) {
    int z = blockIdx.y;
    const float* in = (z == 0) ? Qf : (z == 1) ? Kf : Vf;
    bf16* out = (z == 0) ? Qa : (z == 1) ? Ka : Va;
    size_t i = ((size_t)blockIdx.x * 256 + threadIdx.x) * 8;
    float4 a = *(const float4*)&in[i];
    float4 b = *(const float4*)&in[i + 4];
    bf16x8 o;
    o[0] = f2b(a.x); o[1] = f2b(a.y); o[2] = f2b(a.z); o[3] = f2b(a.w);
    o[4] = f2b(b.x); o[5] = f2b(b.y); o[6] = f2b(b.z); o[7] = f2b(b.w);
    *(bf16x8*)&out[i] = o;
}

// ---------------------------------------------------------------------------
// MFMA GEMM, 128x128 tile, BK=32, 4 waves (2x2 of 64x64), global_load_lds
// width-16 staging (m97 structure). A and Bt both bf16 row-major [.][1024].
// MODE 0: z=0,1,2 -> Qw (x0.125), Kw, VtG (transposed out [1024][4096])
// MODE 1: C=f32 (ctx @ Wo)
// MODE 2: batched z=b: masked logits/16 -> f32 attention_weights
// ---------------------------------------------------------------------------
template <int MODE>
__global__ __launch_bounds__(256) void gemm_k(const bf16* __restrict__ A0,
                                              const bf16* __restrict__ A1,
                                              const bf16* __restrict__ A2,
                                              const bf16* __restrict__ Bt0,
                                              void* __restrict__ C0,
                                              void* __restrict__ C1,
                                              void* __restrict__ C2,
                                              const int* __restrict__ maskp) {
    __shared__ bf16 As[128 * 32];
    __shared__ bf16 Bs[128 * 32];
    int t = threadIdx.x;
    int m0 = blockIdx.x * 128, n0 = blockIdx.y * 128;
    int z = blockIdx.z;
    const bf16* A;
    const bf16* Bt;
    const int* mask = maskp;
    if (MODE == 0) { A = (z == 0) ? A0 : (z == 1) ? A1 : A2; Bt = Bt0 + ((size_t)z << 20); }
    else if (MODE == 1) { A = A0; Bt = Bt0; }
    else { A = A0 + ((size_t)z << 20); Bt = Bt0 + ((size_t)z << 20); mask = maskp + z * 1024; }
    int wid = t >> 6, lane = t & 63;
    int wr = wid >> 1, wc = wid & 1, lr = lane & 15, lg = lane >> 4;
    f32x4 zero = {0.f, 0.f, 0.f, 0.f};
    f32x4 acc[4][4];
#pragma unroll
    for (int m = 0; m < 4; m++)
#pragma unroll
        for (int n = 0; n < 4; n++) acc[m][n] = zero;

    for (int k0 = 0; k0 < 1024; k0 += 32) {
        __syncthreads();
#pragma unroll
        for (int i = 0; i < 2; i++) {
            int c = wid * 128 + i * 64 + lane;
            int row = c >> 2, q = c & 3;
            gl16(&A[(size_t)(m0 + row) * 1024 + k0 + q * 8], (void*)&As[c * 8]);
            gl16(&Bt[(size_t)(n0 + row) * 1024 + k0 + q * 8], (void*)&Bs[c * 8]);
        }
        __syncthreads();
        bf16x8 af[4], bfr[4];
#pragma unroll
        for (int m = 0; m < 4; m++) af[m] = *(const bf16x8*)&As[(wr * 64 + m * 16 + lr) * 32 + lg * 8];
#pragma unroll
        for (int n = 0; n < 4; n++) bfr[n] = *(const bf16x8*)&Bs[(wc * 64 + n * 16 + lr) * 32 + lg * 8];
#pragma unroll
        for (int m = 0; m < 4; m++)
#pragma unroll
            for (int n = 0; n < 4; n++) acc[m][n] = mfma16(af[m], bfr[n], acc[m][n]);
    }
#pragma unroll
    for (int n = 0; n < 4; n++) {
        int colg = n0 + wc * 64 + n * 16 + lr;
        int mk = (MODE == 2) ? mask[colg] : 0;
#pragma unroll
        for (int m = 0; m < 4; m++) {
            int rowg = m0 + wr * 64 + m * 16 + lg * 4;
            if (MODE == 0 && z == 2) {
                bf16x4 o;
#pragma unroll
                for (int j = 0; j < 4; j++) o[j] = f2b(acc[m][n][j]);
                *(bf16x4*)&((bf16*)C2)[(size_t)colg * 4096 + rowg] = o;
            } else {
#pragma unroll
                for (int j = 0; j < 4; j++) {
                    float v = acc[m][n][j];
                    size_t idx = (size_t)(rowg + j) * 1024 + colg;
                    if (MODE == 0) {
                        bf16* C = (bf16*)((z == 0) ? C0 : C1);
                        C[idx] = f2b(v * ((z == 0) ? 0.125f : 1.0f));
                    } else if (MODE == 1) {
                        ((float*)C0)[idx] = v;
                    } else {
                        float* C = (float*)C0 + ((size_t)z << 20);
                        C[idx] = mk ? NEGV : v * (1.f / 16.f);
                    }
                }
            }
        }
    }
}

// ---------------------------------------------------------------------------
// Flash attention v4: per (b, h, 64-row q-tile), 4 waves x 16 q-rows.
// KVBLK=64, LDS 28KB -> 4 blocks/CU all-resident. Swapped QK^T: lane holds
// S[q=lr][k=n*16+4*lg+j] -> per-lane softmax (tree + xor16/32), exp2 domain
// (log2e folded into the bias FMA). P-store vectorized bf16x4, row-XOR
// swizzle everywhere (write and read sides match).
// ---------------------------------------------------------------------------
__global__ __launch_bounds__(256, 4) void flash_k(const bf16* __restrict__ Q,
                                                  const bf16* __restrict__ K,
                                                  const bf16* __restrict__ VT,
                                                  bf16* __restrict__ CTX,
                                                  const int* __restrict__ maskp) {
    __shared__ bf16 Ks[64 * 64];       // [k][d], 128B rows
    __shared__ bf16 Vs[64 * 64];       // [d][k], 128B rows
    __shared__ bf16 Ps[4][16 * 64];    // per-wave [q][k], 128B rows
    __shared__ float biasS[1024];      // mask ? NEGV*log2e : 0
    int bid = blockIdx.x;
    int qt = bid & 15, h = (bid >> 4) & 15, b = bid >> 8;
    int t = threadIdx.x, wid = t >> 6, lane = t & 63;
    int lr = lane & 15, lg = lane >> 4;
    int qbase = qt * 64 + wid * 16;
    const size_t bS = (size_t)b * 1024;
    char* KsB = (char*)Ks;
    char* VsB = (char*)Vs;
    char* PsW = (char*)&Ps[wid][0];
    const int sxl = (lr & 7) << 4;

    {   // mask -> pre-scaled bias table (once per block)
        int4 mv = *(const int4*)&maskp[b * 1024 + t * 4];
        float4 bv;
        const float NB = NEGV * LOG2E;
        bv.x = mv.x ? NB : 0.f; bv.y = mv.y ? NB : 0.f;
        bv.z = mv.z ? NB : 0.f; bv.w = mv.w ? NB : 0.f;
        *(float4*)&biasS[t * 4] = bv;
    }

    bf16x8 qf[2];
#pragma unroll
    for (int c = 0; c < 2; c++)
        qf[c] = *(const bf16x8*)&Q[(bS + qbase + lr) * 1024 + h * 64 + c * 32 + lg * 8];

    f32x4 zero = {0.f, 0.f, 0.f, 0.f};
    f32x4 acc[4];
#pragma unroll
    for (int d = 0; d < 4; d++) acc[d] = zero;
    float mr = -INFINITY;    // running row max (log2 domain), row q = lr
    float lsum = 0.f;        // running row denom

    const bf16* Kbase = K + bS * 1024 + h * 64;
    const bf16* Vbase = VT + (size_t)(h * 64) * 4096 + bS;

    int c0 = t, c1 = t + 256;
    int kr0 = c0 >> 3, kq0 = c0 & 7, kr1 = c1 >> 3, kq1 = c1 & 7;

    bf16x8 kg[2], vg[2];
    kg[0] = *(const bf16x8*)&Kbase[(size_t)kr0 * 1024 + kq0 * 8];
    kg[1] = *(const bf16x8*)&Kbase[(size_t)kr1 * 1024 + kq1 * 8];
    vg[0] = *(const bf16x8*)&Vbase[(size_t)kr0 * 4096 + kq0 * 8];
    vg[1] = *(const bf16x8*)&Vbase[(size_t)kr1 * 4096 + kq1 * 8];

    for (int kt = 0; kt < 16; kt++) {
        __syncthreads();
        *(bf16x8*)(KsB + ((kr0 * 128 + kq0 * 16) ^ ((kr0 & 7) << 4))) = kg[0];
        *(bf16x8*)(KsB + ((kr1 * 128 + kq1 * 16) ^ ((kr1 & 7) << 4))) = kg[1];
        *(bf16x8*)(VsB + ((kr0 * 128 + kq0 * 16) ^ ((kr0 & 7) << 4))) = vg[0];
        *(bf16x8*)(VsB + ((kr1 * 128 + kq1 * 16) ^ ((kr1 & 7) << 4))) = vg[1];
        __syncthreads();
        if (kt < 15) {
            size_t ko = (size_t)(kt + 1) * 64;
            kg[0] = *(const bf16x8*)&Kbase[(ko + kr0) * 1024 + kq0 * 8];
            kg[1] = *(const bf16x8*)&Kbase[(ko + kr1) * 1024 + kq1 * 8];
            vg[0] = *(const bf16x8*)&Vbase[(size_t)kr0 * 4096 + ko + kq0 * 8];
            vg[1] = *(const bf16x8*)&Vbase[(size_t)kr1 * 4096 + ko + kq1 * 8];
        }
        // swapped QK^T: s[n][j] = S[q=lr][k = kt*64 + n*16 + 4*lg + j]
        f32x4 s[4];
        __builtin_amdgcn_s_setprio(1);
#pragma unroll
        for (int n = 0; n < 4; n++) {
            int row = n * 16 + lr;
            bf16x8 kf0 = *(const bf16x8*)(KsB + ((row * 128 + lg * 16) ^ sxl));
            bf16x8 kf1 = *(const bf16x8*)(KsB + ((row * 128 + 64 + lg * 16) ^ sxl));
            f32x4 zz = zero;
            zz = mfma16(kf0, qf[0], zz);
            zz = mfma16(kf1, qf[1], zz);
            s[n] = zz;
        }
        __builtin_amdgcn_s_setprio(0);
        // scale to log2 domain + mask bias, single FMA each
#pragma unroll
        for (int n = 0; n < 4; n++) {
            float4 bv = *(const float4*)&biasS[kt * 64 + n * 16 + lg * 4];
            s[n][0] = __builtin_fmaf(s[n][0], LOG2E, bv.x);
            s[n][1] = __builtin_fmaf(s[n][1], LOG2E, bv.y);
            s[n][2] = __builtin_fmaf(s[n][2], LOG2E, bv.z);
            s[n][3] = __builtin_fmaf(s[n][3], LOG2E, bv.w);
        }
        // per-lane row softmax (row q = lr; 16 values + cross-lg xor16/32)
        float pm;
        {
            float a0 = fmaxf(fmaxf(s[0][0], s[0][1]), fmaxf(s[0][2], s[0][3]));
            float a1 = fmaxf(fmaxf(s[1][0], s[1][1]), fmaxf(s[1][2], s[1][3]));
            float a2 = fmaxf(fmaxf(s[2][0], s[2][1]), fmaxf(s[2][2], s[2][3]));
            float a3 = fmaxf(fmaxf(s[3][0], s[3][1]), fmaxf(s[3][2], s[3][3]));
            pm = fmaxf(fmaxf(a0, a1), fmaxf(a2, a3));
        }
        pm = fmaxf(pm, __shfl_xor(pm, 16));
        pm = fmaxf(pm, __shfl_xor(pm, 32));
        float mn = fmaxf(mr, pm);
        float sc = __builtin_exp2f(mr - mn);
        mr = mn;
        float rs;
        {
            float r0 = 0.f, r1 = 0.f, r2 = 0.f, r3 = 0.f;
#pragma unroll
            for (int n = 0; n < 4; n++) {
                float p0 = __builtin_exp2f(s[n][0] - mn);
                float p1 = __builtin_exp2f(s[n][1] - mn);
                float p2 = __builtin_exp2f(s[n][2] - mn);
                float p3 = __builtin_exp2f(s[n][3] - mn);
                s[n][0] = p0; s[n][1] = p1; s[n][2] = p2; s[n][3] = p3;
                r0 += p0; r1 += p1; r2 += p2; r3 += p3;
            }
            rs = (r0 + r1) + (r2 + r3);
        }
        rs += __shfl_xor(rs, 16);
        rs += __shfl_xor(rs, 32);
        lsum = lsum * sc + rs;
        // broadcast sc to acc-row layout (rows 4*lg+j live at lanes 4*lg+j)
        float scb[4];
#pragma unroll
        for (int j = 0; j < 4; j++) scb[j] = __shfl(sc, lg * 4 + j);
#pragma unroll
        for (int d = 0; d < 4; d++) {
            acc[d][0] *= scb[0]; acc[d][1] *= scb[1];
            acc[d][2] *= scb[2]; acc[d][3] *= scb[3];
        }
        // P -> per-wave LDS, vectorized bf16x4, row-XOR swizzle
#pragma unroll
        for (int n = 0; n < 4; n++) {
            bf16x4 o;
            o[0] = (bf16)s[n][0]; o[1] = (bf16)s[n][1];
            o[2] = (bf16)s[n][2]; o[3] = (bf16)s[n][3];
            *(bf16x4*)(PsW + ((lr * 128 + n * 32 + lg * 8) ^ sxl)) = o;
        }
        // PV
        __builtin_amdgcn_s_setprio(1);
#pragma unroll
        for (int c = 0; c < 2; c++) {
            bf16x8 pa = *(const bf16x8*)(PsW + ((lr * 128 + c * 64 + lg * 16) ^ sxl));
#pragma unroll
            for (int d = 0; d < 4; d++) {
                int row = d * 16 + lr;
                bf16x8 vb = *(const bf16x8*)(VsB + ((row * 128 + c * 64 + lg * 16) ^ ((row & 7) << 4)));
                acc[d] = mfma16(pa, vb, acc[d]);
            }
        }
        __builtin_amdgcn_s_setprio(0);
    }
    // epilogue: rows 4*lg+j; denominators live at lanes 4*lg+j
    float lb[4];
#pragma unroll
    for (int j = 0; j < 4; j++) lb[j] = __shfl(lsum, lg * 4 + j);
#pragma unroll
    for (int j = 0; j < 4; j++) {
        float inv = 1.f / lb[j];
#pragma unroll
        for (int d = 0; d < 4; d++)
            CTX[(bS + qbase + lg * 4 + j) * 1024 + h * 64 + d * 16 + lr] = f2b(acc[d][j] * inv);
    }
}

extern "C" void kernel_launch(void* const* d_in, const int* in_sizes, int n_in,
                              void* d_out, int out_size, void* d_ws, size_t ws_size,
                              hipStream_t stream) {
    const float* queries = (const float*)d_in[0];
    const float* keys    = (const float*)d_in[1];
    const float* values  = (const float*)d_in[2];
    const float* Wq = (const float*)d_in[3];
    const float* Wk = (const float*)d_in[4];
    const float* Wv = (const float*)d_in[5];
    const float* Wo = (const float*)d_in[6];
    const int* mask = (const int*)d_in[7];

    float* out = (float*)d_out;                       // [4,1024,1024]
    float* aw  = out + ((size_t)4 << 20);             // [4,1024,1024]

    bf16* wsb = (bf16*)d_ws;
    bf16* WtQ = wsb;                                  // [0,4M) transposed weights
    bf16* Qa  = wsb + ((size_t)4 << 20);              // activations; reused as CTX
    bf16* Qw  = wsb + ((size_t)8 << 20);
    bf16* Kw  = wsb + ((size_t)12 << 20);
    bf16* VtG = wsb + ((size_t)16 << 20);             // [1024][4096] V transposed
    bf16* Ka  = (bf16*)aw;                            // scratch in aw (written later)
    bf16* Va  = (bf16*)aw + ((size_t)4 << 20);
    bf16* CTX = Qa;

    wconv<<<dim3(16, 16, 4), 256, 0, stream>>>(Wq, Wk, Wv, Wo, WtQ);
    cvt3<<<dim3(2048, 3), 256, 0, stream>>>(queries, keys, values, Qa, Ka, Va);
    gemm_k<0><<<dim3(32, 8, 3), 256, 0, stream>>>(Qa, Ka, Va, WtQ, Qw, Kw, VtG, nullptr);
    gemm_k<2><<<dim3(8, 8, 4), 256, 0, stream>>>(Qw, nullptr, nullptr, Kw, aw, nullptr, nullptr, mask);
    flash_k<<<dim3(1024), 256, 0, stream>>>(Qw, Kw, VtG, CTX, mask);
    gemm_k<1><<<dim3(32, 8, 1), 256, 0, stream>>>(CTX, nullptr, nullptr, WtQ + ((size_t)3 << 20), out, nullptr, nullptr, nullptr);
}

// Round 5
// 116.796 us; speedup vs baseline: 2.4315x; 1.3576x over previous
//
#include <hip/hip_runtime.h>
#include <hip/hip_bf16.h>

typedef __bf16 bf16;
typedef __attribute__((ext_vector_type(8))) __bf16 bf16x8;
typedef __attribute__((ext_vector_type(4))) __bf16 bf16x4;
typedef __attribute__((ext_vector_type(4))) float f32x4;

#define NEGV (-1e18f)
#define LOG2E 1.4426950408889634f

__device__ __forceinline__ bf16 f2b(float f) {
    unsigned u = __builtin_bit_cast(unsigned, f);
    u += 0x7fffu + ((u >> 16) & 1u);
    unsigned short h = (unsigned short)(u >> 16);
    return __builtin_bit_cast(bf16, h);
}

__device__ __forceinline__ f32x4 mfma16(bf16x8 a, bf16x8 b, f32x4 c) {
    return __builtin_amdgcn_mfma_f32_16x16x32_bf16(a, b, c, 0, 0, 0);
}

__device__ __forceinline__ void gl16(const void* g, void* l) {
    __builtin_amdgcn_global_load_lds((const __attribute__((address_space(1))) void*)g,
                                     (__attribute__((address_space(3))) void*)l, 16, 0, 0);
}

// ---------------------------------------------------------------------------
// Weight transpose + f32->bf16 convert: out[w][n][k] = in[w][k][n]
// ---------------------------------------------------------------------------
__global__ __launch_bounds__(256) void wconv(const float* __restrict__ W0,
                                             const float* __restrict__ W1,
                                             const float* __restrict__ W2,
                                             const float* __restrict__ W3,
                                             bf16* __restrict__ out) {
    __shared__ float tile[64][65];
    const float* Ws[4] = {W0, W1, W2, W3};
    const float* W = Ws[blockIdx.z];
    bf16* O = out + ((size_t)blockIdx.z << 20);
    int t = threadIdx.x;
    int k0 = blockIdx.x * 64, n0 = blockIdx.y * 64;
#pragma unroll
    for (int p = 0; p < 4; p++) {
        int r = (t >> 4) + p * 16, c = (t & 15) * 4;
        float4 v = *(const float4*)&W[(size_t)(k0 + r) * 1024 + n0 + c];
        tile[r][c] = v.x; tile[r][c + 1] = v.y; tile[r][c + 2] = v.z; tile[r][c + 3] = v.w;
    }
    __syncthreads();
#pragma unroll
    for (int p = 0; p < 4; p++) {
        int r = (t >> 4) + p * 16, c = (t & 15) * 4;
        bf16x4 o;
        o[0] = f2b(tile[c][r]); o[1] = f2b(tile[c + 1][r]);
        o[2] = f2b(tile[c + 2][r]); o[3] = f2b(tile[c + 3][r]);
        *(bf16x4*)&O[(size_t)(n0 + r) * 1024 + k0 + c] = o;
    }
}

// ---------------------------------------------------------------------------
// Projection GEMM with fused f32->bf16 A-staging. 128x128 tile, BK=64,
// 4 waves (2x2 of 64x64). B staged via global_load_lds w16 with pre-swizzled
// source column (linear LDS dest, rule #21); A reg-prefetched one K-step
// ahead, converted, ds_write_b128 to the swizzled slot. Reads use
// byte ^ ((row&7)<<4). z=0: Qw*0.125, z=1: Kw, z=2: VtG (transposed out).
// ---------------------------------------------------------------------------
__global__ __launch_bounds__(256, 3) void gemm_proj(const float* __restrict__ Qf,
                                                    const float* __restrict__ Kf,
                                                    const float* __restrict__ Vf,
                                                    const bf16* __restrict__ WtQ,
                                                    bf16* __restrict__ Qw,
                                                    bf16* __restrict__ Kw,
                                                    bf16* __restrict__ VtG) {
    __shared__ bf16 As[128 * 64];
    __shared__ bf16 Bs[128 * 64];
    char* AsB = (char*)As;
    char* BsB = (char*)Bs;
    int t = threadIdx.x;
    int m0 = blockIdx.x * 128, n0 = blockIdx.y * 128;
    int z = blockIdx.z;
    const float* A = (z == 0) ? Qf : (z == 1) ? Kf : Vf;
    const bf16* Bt = WtQ + ((size_t)z << 20);
    int wid = t >> 6, lane = t & 63;
    int wr = wid >> 1, wc = wid & 1, lr = lane & 15, lg = lane >> 4;
    f32x4 zero = {0.f, 0.f, 0.f, 0.f};
    f32x4 acc[4][4];
#pragma unroll
    for (int m = 0; m < 4; m++)
#pragma unroll
        for (int n = 0; n < 4; n++) acc[m][n] = zero;

    float4 pa[4][2];
#pragma unroll
    for (int i = 0; i < 4; i++) {
        int c = wid * 256 + i * 64 + lane;
        int row = c >> 3, q = c & 7;
        const float* src = &A[(size_t)(m0 + row) * 1024 + q * 8];
        pa[i][0] = *(const float4*)src;
        pa[i][1] = *(const float4*)(src + 4);
    }

    for (int k0 = 0; k0 < 1024; k0 += 64) {
        __syncthreads();
#pragma unroll
        for (int i = 0; i < 4; i++) {   // B: async gl16, pre-swizzled source col
            int c = wid * 256 + i * 64 + lane;
            int row = c >> 3, q = (c & 7) ^ (row & 7);
            gl16(&Bt[(size_t)(n0 + row) * 1024 + k0 + q * 8], (void*)&Bs[c * 8]);
        }
#pragma unroll
        for (int i = 0; i < 4; i++) {   // A: cvt prefetched regs, swizzled write
            int c = wid * 256 + i * 64 + lane;
            int row = c >> 3;
            bf16x8 o;
            o[0] = f2b(pa[i][0].x); o[1] = f2b(pa[i][0].y);
            o[2] = f2b(pa[i][0].z); o[3] = f2b(pa[i][0].w);
            o[4] = f2b(pa[i][1].x); o[5] = f2b(pa[i][1].y);
            o[6] = f2b(pa[i][1].z); o[7] = f2b(pa[i][1].w);
            *(bf16x8*)(AsB + ((c * 16) ^ ((row & 7) << 4))) = o;
        }
        __syncthreads();
        if (k0 < 960) {                 // prefetch next A under the MFMA phase
#pragma unroll
            for (int i = 0; i < 4; i++) {
                int c = wid * 256 + i * 64 + lane;
                int row = c >> 3, q = c & 7;
                const float* src = &A[(size_t)(m0 + row) * 1024 + k0 + 64 + q * 8];
                pa[i][0] = *(const float4*)src;
                pa[i][1] = *(const float4*)(src + 4);
            }
        }
#pragma unroll
        for (int kk = 0; kk < 2; kk++) {
            bf16x8 af[4], bfr[4];
#pragma unroll
            for (int m = 0; m < 4; m++) {
                int row = wr * 64 + m * 16 + lr;
                af[m] = *(const bf16x8*)(AsB + ((row * 128 + kk * 64 + lg * 16) ^ ((row & 7) << 4)));
            }
#pragma unroll
            for (int n = 0; n < 4; n++) {
                int row = wc * 64 + n * 16 + lr;
                bfr[n] = *(const bf16x8*)(BsB + ((row * 128 + kk * 64 + lg * 16) ^ ((row & 7) << 4)));
            }
#pragma unroll
            for (int m = 0; m < 4; m++)
#pragma unroll
                for (int n = 0; n < 4; n++) acc[m][n] = mfma16(af[m], bfr[n], acc[m][n]);
        }
    }
#pragma unroll
    for (int n = 0; n < 4; n++) {
        int colg = n0 + wc * 64 + n * 16 + lr;
#pragma unroll
        for (int m = 0; m < 4; m++) {
            int rowg = m0 + wr * 64 + m * 16 + lg * 4;
            if (z == 2) {
                bf16x4 o;
#pragma unroll
                for (int j = 0; j < 4; j++) o[j] = f2b(acc[m][n][j]);
                *(bf16x4*)&VtG[(size_t)colg * 4096 + rowg] = o;
            } else {
                bf16* C = (z == 0) ? Qw : Kw;
                float sc = (z == 0) ? 0.125f : 1.0f;
#pragma unroll
                for (int j = 0; j < 4; j++)
                    C[(size_t)(rowg + j) * 1024 + colg] = f2b(acc[m][n][j] * sc);
            }
        }
    }
}

// ---------------------------------------------------------------------------
// Merged output GEMM + attention_weights GEMM. grid (32,8,2), BK=64,
// both operands bf16 via gl16 with pre-swizzled source.
// z=0: out = CTX @ Wo (f32).  z=1: b=x>>3, mx=x&7: aw[b] = masked(Qw Kw^T)/16.
// ---------------------------------------------------------------------------
__global__ __launch_bounds__(256, 3) void gemm_oa(const bf16* __restrict__ CTX,
                                                  const bf16* __restrict__ WtO,
                                                  float* __restrict__ out,
                                                  const bf16* __restrict__ Qw,
                                                  const bf16* __restrict__ Kw,
                                                  float* __restrict__ aw,
                                                  const int* __restrict__ maskp) {
    __shared__ bf16 As[128 * 64];
    __shared__ bf16 Bs[128 * 64];
    char* AsB = (char*)As;
    char* BsB = (char*)Bs;
    int t = threadIdx.x;
    int z = blockIdx.z;
    int bx = blockIdx.x;
    int m0, n0 = blockIdx.y * 128;
    const bf16* A;
    const bf16* Bt;
    float* C;
    const int* mask = nullptr;
    if (z == 0) {
        m0 = bx * 128;
        A = CTX; Bt = WtO; C = out;
    } else {
        int b = bx >> 3;
        m0 = (bx & 7) * 128;
        A = Qw + ((size_t)b << 20); Bt = Kw + ((size_t)b << 20);
        C = aw + ((size_t)b << 20); mask = maskp + b * 1024;
    }
    int wid = t >> 6, lane = t & 63;
    int wr = wid >> 1, wc = wid & 1, lr = lane & 15, lg = lane >> 4;
    f32x4 zero = {0.f, 0.f, 0.f, 0.f};
    f32x4 acc[4][4];
#pragma unroll
    for (int m = 0; m < 4; m++)
#pragma unroll
        for (int n = 0; n < 4; n++) acc[m][n] = zero;

    for (int k0 = 0; k0 < 1024; k0 += 64) {
        __syncthreads();
#pragma unroll
        for (int i = 0; i < 4; i++) {
            int c = wid * 256 + i * 64 + lane;
            int row = c >> 3, q = (c & 7) ^ (row & 7);
            gl16(&A[(size_t)(m0 + row) * 1024 + k0 + q * 8], (void*)&As[c * 8]);
            gl16(&Bt[(size_t)(n0 + row) * 1024 + k0 + q * 8], (void*)&Bs[c * 8]);
        }
        __syncthreads();
#pragma unroll
        for (int kk = 0; kk < 2; kk++) {
            bf16x8 af[4], bfr[4];
#pragma unroll
            for (int m = 0; m < 4; m++) {
                int row = wr * 64 + m * 16 + lr;
                af[m] = *(const bf16x8*)(AsB + ((row * 128 + kk * 64 + lg * 16) ^ ((row & 7) << 4)));
            }
#pragma unroll
            for (int n = 0; n < 4; n++) {
                int row = wc * 64 + n * 16 + lr;
                bfr[n] = *(const bf16x8*)(BsB + ((row * 128 + kk * 64 + lg * 16) ^ ((row & 7) << 4)));
            }
#pragma unroll
            for (int m = 0; m < 4; m++)
#pragma unroll
                for (int n = 0; n < 4; n++) acc[m][n] = mfma16(af[m], bfr[n], acc[m][n]);
        }
    }
#pragma unroll
    for (int n = 0; n < 4; n++) {
        int colg = n0 + wc * 64 + n * 16 + lr;
        int mk = (z == 1) ? mask[colg] : 0;
#pragma unroll
        for (int m = 0; m < 4; m++) {
            int rowg = m0 + wr * 64 + m * 16 + lg * 4;
#pragma unroll
            for (int j = 0; j < 4; j++) {
                float v = acc[m][n][j];
                size_t idx = (size_t)(rowg + j) * 1024 + colg;
                if (z == 0) C[idx] = v;
                else C[idx] = mk ? NEGV : v * (1.f / 16.f);
            }
        }
    }
}

// ---------------------------------------------------------------------------
// Flash attention v4 (unchanged from round 4): per (b, h, 64-row q-tile),
// KVBLK=64, swapped QK^T, exp2-domain softmax, row-XOR swizzled LDS.
// ---------------------------------------------------------------------------
__global__ __launch_bounds__(256, 4) void flash_k(const bf16* __restrict__ Q,
                                                  const bf16* __restrict__ K,
                                                  const bf16* __restrict__ VT,
                                                  bf16* __restrict__ CTX,
                                                  const int* __restrict__ maskp) {
    __shared__ bf16 Ks[64 * 64];
    __shared__ bf16 Vs[64 * 64];
    __shared__ bf16 Ps[4][16 * 64];
    __shared__ float biasS[1024];
    int bid = blockIdx.x;
    int qt = bid & 15, h = (bid >> 4) & 15, b = bid >> 8;
    int t = threadIdx.x, wid = t >> 6, lane = t & 63;
    int lr = lane & 15, lg = lane >> 4;
    int qbase = qt * 64 + wid * 16;
    const size_t bS = (size_t)b * 1024;
    char* KsB = (char*)Ks;
    char* VsB = (char*)Vs;
    char* PsW = (char*)&Ps[wid][0];
    const int sxl = (lr & 7) << 4;

    {
        int4 mv = *(const int4*)&maskp[b * 1024 + t * 4];
        float4 bv;
        const float NB = NEGV * LOG2E;
        bv.x = mv.x ? NB : 0.f; bv.y = mv.y ? NB : 0.f;
        bv.z = mv.z ? NB : 0.f; bv.w = mv.w ? NB : 0.f;
        *(float4*)&biasS[t * 4] = bv;
    }

    bf16x8 qf[2];
#pragma unroll
    for (int c = 0; c < 2; c++)
        qf[c] = *(const bf16x8*)&Q[(bS + qbase + lr) * 1024 + h * 64 + c * 32 + lg * 8];

    f32x4 zero = {0.f, 0.f, 0.f, 0.f};
    f32x4 acc[4];
#pragma unroll
    for (int d = 0; d < 4; d++) acc[d] = zero;
    float mr = -INFINITY;
    float lsum = 0.f;

    const bf16* Kbase = K + bS * 1024 + h * 64;
    const bf16* Vbase = VT + (size_t)(h * 64) * 4096 + bS;

    int c0 = t, c1 = t + 256;
    int kr0 = c0 >> 3, kq0 = c0 & 7, kr1 = c1 >> 3, kq1 = c1 & 7;

    bf16x8 kg[2], vg[2];
    kg[0] = *(const bf16x8*)&Kbase[(size_t)kr0 * 1024 + kq0 * 8];
    kg[1] = *(const bf16x8*)&Kbase[(size_t)kr1 * 1024 + kq1 * 8];
    vg[0] = *(const bf16x8*)&Vbase[(size_t)kr0 * 4096 + kq0 * 8];
    vg[1] = *(const bf16x8*)&Vbase[(size_t)kr1 * 4096 + kq1 * 8];

    for (int kt = 0; kt < 16; kt++) {
        __syncthreads();
        *(bf16x8*)(KsB + ((kr0 * 128 + kq0 * 16) ^ ((kr0 & 7) << 4))) = kg[0];
        *(bf16x8*)(KsB + ((kr1 * 128 + kq1 * 16) ^ ((kr1 & 7) << 4))) = kg[1];
        *(bf16x8*)(VsB + ((kr0 * 128 + kq0 * 16) ^ ((kr0 & 7) << 4))) = vg[0];
        *(bf16x8*)(VsB + ((kr1 * 128 + kq1 * 16) ^ ((kr1 & 7) << 4))) = vg[1];
        __syncthreads();
        if (kt < 15) {
            size_t ko = (size_t)(kt + 1) * 64;
            kg[0] = *(const bf16x8*)&Kbase[(ko + kr0) * 1024 + kq0 * 8];
            kg[1] = *(const bf16x8*)&Kbase[(ko + kr1) * 1024 + kq1 * 8];
            vg[0] = *(const bf16x8*)&Vbase[(size_t)kr0 * 4096 + ko + kq0 * 8];
            vg[1] = *(const bf16x8*)&Vbase[(size_t)kr1 * 4096 + ko + kq1 * 8];
        }
        f32x4 s[4];
        __builtin_amdgcn_s_setprio(1);
#pragma unroll
        for (int n = 0; n < 4; n++) {
            int row = n * 16 + lr;
            bf16x8 kf0 = *(const bf16x8*)(KsB + ((row * 128 + lg * 16) ^ sxl));
            bf16x8 kf1 = *(const bf16x8*)(KsB + ((row * 128 + 64 + lg * 16) ^ sxl));
            f32x4 zz = zero;
            zz = mfma16(kf0, qf[0], zz);
            zz = mfma16(kf1, qf[1], zz);
            s[n] = zz;
        }
        __builtin_amdgcn_s_setprio(0);
#pragma unroll
        for (int n = 0; n < 4; n++) {
            float4 bv = *(const float4*)&biasS[kt * 64 + n * 16 + lg * 4];
            s[n][0] = __builtin_fmaf(s[n][0], LOG2E, bv.x);
            s[n][1] = __builtin_fmaf(s[n][1], LOG2E, bv.y);
            s[n][2] = __builtin_fmaf(s[n][2], LOG2E, bv.z);
            s[n][3] = __builtin_fmaf(s[n][3], LOG2E, bv.w);
        }
        float pm;
        {
            float a0 = fmaxf(fmaxf(s[0][0], s[0][1]), fmaxf(s[0][2], s[0][3]));
            float a1 = fmaxf(fmaxf(s[1][0], s[1][1]), fmaxf(s[1][2], s[1][3]));
            float a2 = fmaxf(fmaxf(s[2][0], s[2][1]), fmaxf(s[2][2], s[2][3]));
            float a3 = fmaxf(fmaxf(s[3][0], s[3][1]), fmaxf(s[3][2], s[3][3]));
            pm = fmaxf(fmaxf(a0, a1), fmaxf(a2, a3));
        }
        pm = fmaxf(pm, __shfl_xor(pm, 16));
        pm = fmaxf(pm, __shfl_xor(pm, 32));
        float mn = fmaxf(mr, pm);
        float sc = __builtin_exp2f(mr - mn);
        mr = mn;
        float rs;
        {
            float r0 = 0.f, r1 = 0.f, r2 = 0.f, r3 = 0.f;
#pragma unroll
            for (int n = 0; n < 4; n++) {
                float p0 = __builtin_exp2f(s[n][0] - mn);
                float p1 = __builtin_exp2f(s[n][1] - mn);
                float p2 = __builtin_exp2f(s[n][2] - mn);
                float p3 = __builtin_exp2f(s[n][3] - mn);
                s[n][0] = p0; s[n][1] = p1; s[n][2] = p2; s[n][3] = p3;
                r0 += p0; r1 += p1; r2 += p2; r3 += p3;
            }
            rs = (r0 + r1) + (r2 + r3);
        }
        rs += __shfl_xor(rs, 16);
        rs += __shfl_xor(rs, 32);
        lsum = lsum * sc + rs;
        float scb[4];
#pragma unroll
        for (int j = 0; j < 4; j++) scb[j] = __shfl(sc, lg * 4 + j);
#pragma unroll
        for (int d = 0; d < 4; d++) {
            acc[d][0] *= scb[0]; acc[d][1] *= scb[1];
            acc[d][2] *= scb[2]; acc[d][3] *= scb[3];
        }
#pragma unroll
        for (int n = 0; n < 4; n++) {
            bf16x4 o;
            o[0] = (bf16)s[n][0]; o[1] = (bf16)s[n][1];
            o[2] = (bf16)s[n][2]; o[3] = (bf16)s[n][3];
            *(bf16x4*)(PsW + ((lr * 128 + n * 32 + lg * 8) ^ sxl)) = o;
        }
        __builtin_amdgcn_s_setprio(1);
#pragma unroll
        for (int c = 0; c < 2; c++) {
            bf16x8 pa = *(const bf16x8*)(PsW + ((lr * 128 + c * 64 + lg * 16) ^ sxl));
#pragma unroll
            for (int d = 0; d < 4; d++) {
                int row = d * 16 + lr;
                bf16x8 vb = *(const bf16x8*)(VsB + ((row * 128 + c * 64 + lg * 16) ^ ((row & 7) << 4)));
                acc[d] = mfma16(pa, vb, acc[d]);
            }
        }
        __builtin_amdgcn_s_setprio(0);
    }
    float lb[4];
#pragma unroll
    for (int j = 0; j < 4; j++) lb[j] = __shfl(lsum, lg * 4 + j);
#pragma unroll
    for (int j = 0; j < 4; j++) {
        float inv = 1.f / lb[j];
#pragma unroll
        for (int d = 0; d < 4; d++)
            CTX[(bS + qbase + lg * 4 + j) * 1024 + h * 64 + d * 16 + lr] = f2b(acc[d][j] * inv);
    }
}

extern "C" void kernel_launch(void* const* d_in, const int* in_sizes, int n_in,
                              void* d_out, int out_size, void* d_ws, size_t ws_size,
                              hipStream_t stream) {
    const float* queries = (const float*)d_in[0];
    const float* keys    = (const float*)d_in[1];
    const float* values  = (const float*)d_in[2];
    const float* Wq = (const float*)d_in[3];
    const float* Wk = (const float*)d_in[4];
    const float* Wv = (const float*)d_in[5];
    const float* Wo = (const float*)d_in[6];
    const int* mask = (const int*)d_in[7];

    float* out = (float*)d_out;                       // [4,1024,1024]
    float* aw  = out + ((size_t)4 << 20);             // [4,1024,1024]

    bf16* wsb = (bf16*)d_ws;
    bf16* WtQ = wsb;                                  // [0,4M) transposed weights (Q,K,V,O)
    bf16* Qw  = wsb + ((size_t)4 << 20);
    bf16* Kw  = wsb + ((size_t)8 << 20);
    bf16* VtG = wsb + ((size_t)12 << 20);             // [1024][4096] V transposed
    bf16* CTX = wsb + ((size_t)16 << 20);

    wconv<<<dim3(16, 16, 4), 256, 0, stream>>>(Wq, Wk, Wv, Wo, WtQ);
    gemm_proj<<<dim3(32, 8, 3), 256, 0, stream>>>(queries, keys, values, WtQ, Qw, Kw, VtG);
    flash_k<<<dim3(1024), 256, 0, stream>>>(Qw, Kw, VtG, CTX, mask);
    gemm_oa<<<dim3(32, 8, 2), 256, 0, stream>>>(CTX, WtQ + ((size_t)3 << 20), out,
                                                Qw, Kw, aw, mask);
}